// Round 5
// baseline (7840.327 us; speedup 1.0000x reference)
//
#include <hip/hip_runtime.h>
#include <math.h>

#define N 512
#define NITERS 100
#define SC 10.0f

// round-to-nearest-even fp32 -> bf16 pair packed into one uint
__device__ __forceinline__ unsigned int pack_bf16(float a, float b) {
    unsigned int ua = __float_as_uint(a);
    unsigned int ub = __float_as_uint(b);
    ua = (ua + 0x7fffu + ((ua >> 16) & 1u)) >> 16;
    ub = (ub + 0x7fffu + ((ub >> 16) & 1u)) >> 16;
    return ua | (ub << 16);
}

// One block (1024 thr, 16 waves) per matrix. Multiplicative Sinkhorn on a
// precomputed bf16 kernel K' = exp(A*SC - rowmax_i), stored in this block's
// own d_out region. Iteration (algebraically == round-4's w/c update):
//   s_i = sum_j K'_ij w_j ; r_i = 1/s_i ; t_j = sum_i K'_ij r_i ; w_j = 1/t_j
// Latency fix vs round 4: 8-row register batches -> 8 loads in flight,
// 8 interleaved butterfly reductions (chains overlap), row data reused from
// registers for the t-pass (K' still read exactly once per iteration).
__global__ __launch_bounds__(1024, 1)
void sinkhorn_batch(const float* __restrict__ X, float* __restrict__ P) {
    __shared__ float w_s[N];        // column scaling w
    __shared__ float m_s[N];        // rowmax of A*SC
    __shared__ float lnS_s[N];      // ln(row sum) at final row pass
    __shared__ float c_lds[16 * N]; // per-wave t partials

    const int tid  = threadIdx.x;
    const int lane = tid & 63;
    const int wave = tid >> 6;          // 0..15

    const size_t base = (size_t)blockIdx.x * N * N;
    const float* __restrict__ A   = X + base;
    float*       __restrict__ out = P + base;
    unsigned short* __restrict__ Kb = (unsigned short*)(P + base);  // 512 KB own region

    if (tid < N) w_s[tid] = 1.0f;

    // ---- precompute K' = exp(A*SC - rowmax) in bf16; rowmax -> m_s ----
    #pragma unroll 1
    for (int r = wave; r < N; r += 16) {
        const float4* rowp = (const float4*)(A + (size_t)r * N);
        float4 a0 = rowp[lane];          // cols 4L..4L+3
        float4 a1 = rowp[lane + 64];     // cols 256+4L..
        float x0 = a0.x * SC, x1 = a0.y * SC, x2 = a0.z * SC, x3 = a0.w * SC;
        float x4 = a1.x * SC, x5 = a1.y * SC, x6 = a1.z * SC, x7 = a1.w * SC;
        float mx = fmaxf(fmaxf(fmaxf(x0, x1), fmaxf(x2, x3)),
                         fmaxf(fmaxf(x4, x5), fmaxf(x6, x7)));
        #pragma unroll
        for (int o = 32; o > 0; o >>= 1) mx = fmaxf(mx, __shfl_xor(mx, o, 64));
        uint2 p0, p1;
        p0.x = pack_bf16(__expf(x0 - mx), __expf(x1 - mx));
        p0.y = pack_bf16(__expf(x2 - mx), __expf(x3 - mx));
        p1.x = pack_bf16(__expf(x4 - mx), __expf(x5 - mx));
        p1.y = pack_bf16(__expf(x6 - mx), __expf(x7 - mx));
        uint2* krow = (uint2*)(Kb + (size_t)r * N);
        krow[lane]      = p0;
        krow[lane + 64] = p1;
        if (lane == 0) m_s[r] = mx;
    }
    __threadfence();
    __syncthreads();

    // ---- 100 iterations ----
    const size_t RS = (size_t)16 * N;   // ushorts between this wave's rows
    for (int it = 0; it < NITERS; ++it) {
        const bool last = (it == NITERS - 1);
        const float4 w0 = *(const float4*)(w_s + 8 * lane);      // cols 8L..8L+3
        const float4 w1 = *(const float4*)(w_s + 8 * lane + 4);  // cols 8L+4..8L+7
        float t0 = 0.f, t1 = 0.f, t2 = 0.f, t3 = 0.f,
              t4 = 0.f, t5 = 0.f, t6 = 0.f, t7 = 0.f;

        const unsigned short* kp = Kb + (size_t)wave * N;
        uint4 cur[8], nxt[8];
        #pragma unroll
        for (int k = 0; k < 8; ++k)
            cur[k] = ((const uint4*)(kp + (size_t)k * RS))[lane];

        #pragma unroll
        for (int b = 0; b < 4; ++b) {
            const unsigned short* np = kp + 8 * RS;
            if (b < 3) {
                #pragma unroll
                for (int k = 0; k < 8; ++k)
                    nxt[k] = ((const uint4*)(np + (size_t)k * RS))[lane];
            }
            // pass 1: 8 independent row sums (no cross-lane yet)
            float s[8];
            #pragma unroll
            for (int k = 0; k < 8; ++k) {
                float f0 = __uint_as_float(cur[k].x << 16);
                float f1 = __uint_as_float(cur[k].x & 0xffff0000u);
                float f2 = __uint_as_float(cur[k].y << 16);
                float f3 = __uint_as_float(cur[k].y & 0xffff0000u);
                float f4 = __uint_as_float(cur[k].z << 16);
                float f5 = __uint_as_float(cur[k].z & 0xffff0000u);
                float f6 = __uint_as_float(cur[k].w << 16);
                float f7 = __uint_as_float(cur[k].w & 0xffff0000u);
                float sa = f0 * w0.x;
                sa = fmaf(f2, w0.z, sa);
                sa = fmaf(f4, w1.x, sa);
                sa = fmaf(f6, w1.z, sa);
                float sb = f1 * w0.y;
                sb = fmaf(f3, w0.w, sb);
                sb = fmaf(f5, w1.y, sb);
                sb = fmaf(f7, w1.w, sb);
                s[k] = sa + sb;
            }
            // 8 interleaved butterfly reductions: chains overlap, no stalls
            #pragma unroll
            for (int o = 32; o > 0; o >>= 1) {
                #pragma unroll
                for (int k = 0; k < 8; ++k)
                    s[k] += __shfl_xor(s[k], o, 64);
            }
            if (last && lane == 0) {
                #pragma unroll
                for (int k = 0; k < 8; ++k)
                    lnS_s[wave + 16 * (8 * b + k)] = __logf(s[k]);
            }
            #pragma unroll
            for (int k = 0; k < 8; ++k) s[k] = __builtin_amdgcn_rcpf(s[k]);
            // pass 2: t_j += K'_ij * r_i from registers (pure fma streaming)
            #pragma unroll
            for (int k = 0; k < 8; ++k) {
                const float r = s[k];
                float f0 = __uint_as_float(cur[k].x << 16);
                float f1 = __uint_as_float(cur[k].x & 0xffff0000u);
                float f2 = __uint_as_float(cur[k].y << 16);
                float f3 = __uint_as_float(cur[k].y & 0xffff0000u);
                float f4 = __uint_as_float(cur[k].z << 16);
                float f5 = __uint_as_float(cur[k].z & 0xffff0000u);
                float f6 = __uint_as_float(cur[k].w << 16);
                float f7 = __uint_as_float(cur[k].w & 0xffff0000u);
                t0 = fmaf(f0, r, t0); t1 = fmaf(f1, r, t1);
                t2 = fmaf(f2, r, t2); t3 = fmaf(f3, r, t3);
                t4 = fmaf(f4, r, t4); t5 = fmaf(f5, r, t5);
                t6 = fmaf(f6, r, t6); t7 = fmaf(f7, r, t7);
            }
            #pragma unroll
            for (int k = 0; k < 8; ++k) cur[k] = nxt[k];
            kp = np;
        }

        // cross-wave t reduction (measured: bank conflicts here are ~0.7% - ignore)
        *(float4*)(c_lds + wave * N + 8 * lane)     = make_float4(t0, t1, t2, t3);
        *(float4*)(c_lds + wave * N + 8 * lane + 4) = make_float4(t4, t5, t6, t7);
        __syncthreads();
        if (tid < N) {
            float cs = 0.f;
            #pragma unroll
            for (int w = 0; w < 16; ++w) cs += c_lds[w * N + tid];
            w_s[tid] = __builtin_amdgcn_rcpf(fmaxf(cs, 1e-38f));
        }
        __syncthreads();
    }

    // ---- epilogue: P = exp(A*SC - m_i - lnS_i + ln w_j) from fp32 A ----
    float* g_s  = c_lds;        // ln w  [N]
    float* rt_s = c_lds + N;    // -(m + lnS) [N]
    if (tid < N) {
        g_s[tid]  = __logf(w_s[tid]);
        rt_s[tid] = -(m_s[tid] + lnS_s[tid]);
    }
    __syncthreads();

    #pragma unroll 1
    for (int r = wave; r < N; r += 16) {
        const float rt = rt_s[r];
        const float4* rowp = (const float4*)(A + (size_t)r * N);
        float4 a0 = rowp[lane];
        float4 a1 = rowp[lane + 64];
        float4 g0 = *(const float4*)(g_s + 4 * lane);
        float4 g1 = *(const float4*)(g_s + 256 + 4 * lane);
        float4 o0, o1;
        o0.x = __expf(fmaf(a0.x, SC, rt) + g0.x);
        o0.y = __expf(fmaf(a0.y, SC, rt) + g0.y);
        o0.z = __expf(fmaf(a0.z, SC, rt) + g0.z);
        o0.w = __expf(fmaf(a0.w, SC, rt) + g0.w);
        o1.x = __expf(fmaf(a1.x, SC, rt) + g1.x);
        o1.y = __expf(fmaf(a1.y, SC, rt) + g1.y);
        o1.z = __expf(fmaf(a1.z, SC, rt) + g1.z);
        o1.w = __expf(fmaf(a1.w, SC, rt) + g1.w);
        float4* outp = (float4*)(out + (size_t)r * N);
        outp[lane]      = o0;
        outp[lane + 64] = o1;
    }
}

extern "C" void kernel_launch(void* const* d_in, const int* in_sizes, int n_in,
                              void* d_out, int out_size, void* d_ws, size_t ws_size,
                              hipStream_t stream) {
    const float* X = (const float*)d_in[0];
    float* P = (float*)d_out;
    const int batch = in_sizes[0] / (N * N);   // 128
    hipLaunchKernelGGL(sinkhorn_batch, dim3(batch), dim3(1024), 0, stream, X, P);
}

// Round 6
// 7812.483 us; speedup vs baseline: 1.0036x; 1.0036x over previous
//
#include <hip/hip_runtime.h>
#include <math.h>

#define N 512
#define NITERS 100
#define SC 10.0f

// round-to-nearest-even fp32 -> bf16 pair packed into one uint
__device__ __forceinline__ unsigned int pack_bf16(float a, float b) {
    unsigned int ua = __float_as_uint(a);
    unsigned int ub = __float_as_uint(b);
    ua = (ua + 0x7fffu + ((ua >> 16) & 1u)) >> 16;
    ub = (ub + 0x7fffu + ((ub >> 16) & 1u)) >> 16;
    return ua | (ub << 16);
}

// One block (1024 thr, 16 waves) per matrix. Multiplicative Sinkhorn on a
// precomputed bf16 kernel K' = exp(A*SC - rowmax_i), stored in this block's
// own d_out region:
//   s_i = sum_j K'_ij w_j ; r_i = 1/s_i ; t_j = sum_i K'_ij r_i ; w_j = 1/t_j
// 8-row register batches: 8 loads in flight, 8 interleaved butterfly chains,
// K' read once per iteration (t-pass reuses registers).
// __launch_bounds__(1024, 4): 4 waves/EU -> 128-VGPR cap. Round 5 used (1024,1)
// which left the default 64-VGPR cap -> full spill of the batch arrays
// (WRITE_SIZE 196K -> 9.5M KB). Do not lower the second argument.
__global__ __launch_bounds__(1024, 4)
void sinkhorn_batch(const float* __restrict__ X, float* __restrict__ P) {
    __shared__ float w_s[N];        // column scaling w
    __shared__ float m_s[N];        // rowmax of A*SC
    __shared__ float lnS_s[N];      // ln(row sum) at final row pass
    __shared__ float c_lds[16 * N]; // per-wave t partials

    const int tid  = threadIdx.x;
    const int lane = tid & 63;
    const int wave = tid >> 6;          // 0..15

    const size_t base = (size_t)blockIdx.x * N * N;
    const float* __restrict__ A   = X + base;
    float*       __restrict__ out = P + base;
    unsigned short* __restrict__ Kb = (unsigned short*)(P + base);  // 512 KB own region

    if (tid < N) w_s[tid] = 1.0f;

    // ---- precompute K' = exp(A*SC - rowmax) in bf16; rowmax -> m_s ----
    #pragma unroll 1
    for (int r = wave; r < N; r += 16) {
        const float4* rowp = (const float4*)(A + (size_t)r * N);
        float4 a0 = rowp[lane];          // cols 4L..4L+3
        float4 a1 = rowp[lane + 64];     // cols 256+4L..
        float x0 = a0.x * SC, x1 = a0.y * SC, x2 = a0.z * SC, x3 = a0.w * SC;
        float x4 = a1.x * SC, x5 = a1.y * SC, x6 = a1.z * SC, x7 = a1.w * SC;
        float mx = fmaxf(fmaxf(fmaxf(x0, x1), fmaxf(x2, x3)),
                         fmaxf(fmaxf(x4, x5), fmaxf(x6, x7)));
        #pragma unroll
        for (int o = 32; o > 0; o >>= 1) mx = fmaxf(mx, __shfl_xor(mx, o, 64));
        uint2 p0, p1;
        p0.x = pack_bf16(__expf(x0 - mx), __expf(x1 - mx));
        p0.y = pack_bf16(__expf(x2 - mx), __expf(x3 - mx));
        p1.x = pack_bf16(__expf(x4 - mx), __expf(x5 - mx));
        p1.y = pack_bf16(__expf(x6 - mx), __expf(x7 - mx));
        uint2* krow = (uint2*)(Kb + (size_t)r * N);
        krow[lane]      = p0;
        krow[lane + 64] = p1;
        if (lane == 0) m_s[r] = mx;
    }
    __threadfence();
    __syncthreads();

    // ---- 100 iterations ----
    const size_t RS = (size_t)16 * N;   // ushorts between this wave's rows
    for (int it = 0; it < NITERS; ++it) {
        const bool last = (it == NITERS - 1);
        const float4 w0 = *(const float4*)(w_s + 8 * lane);      // cols 8L..8L+3
        const float4 w1 = *(const float4*)(w_s + 8 * lane + 4);  // cols 8L+4..8L+7
        float t0 = 0.f, t1 = 0.f, t2 = 0.f, t3 = 0.f,
              t4 = 0.f, t5 = 0.f, t6 = 0.f, t7 = 0.f;

        const unsigned short* kp = Kb + (size_t)wave * N;
        uint4 cur[8], nxt[8];
        #pragma unroll
        for (int k = 0; k < 8; ++k)
            cur[k] = ((const uint4*)(kp + (size_t)k * RS))[lane];

        #pragma unroll
        for (int b = 0; b < 4; ++b) {
            const unsigned short* np = kp + 8 * RS;
            if (b < 3) {
                #pragma unroll
                for (int k = 0; k < 8; ++k)
                    nxt[k] = ((const uint4*)(np + (size_t)k * RS))[lane];
            }
            // pass 1: 8 independent row sums (no cross-lane yet)
            float s[8];
            #pragma unroll
            for (int k = 0; k < 8; ++k) {
                float f0 = __uint_as_float(cur[k].x << 16);
                float f1 = __uint_as_float(cur[k].x & 0xffff0000u);
                float f2 = __uint_as_float(cur[k].y << 16);
                float f3 = __uint_as_float(cur[k].y & 0xffff0000u);
                float f4 = __uint_as_float(cur[k].z << 16);
                float f5 = __uint_as_float(cur[k].z & 0xffff0000u);
                float f6 = __uint_as_float(cur[k].w << 16);
                float f7 = __uint_as_float(cur[k].w & 0xffff0000u);
                float sa = f0 * w0.x;
                sa = fmaf(f2, w0.z, sa);
                sa = fmaf(f4, w1.x, sa);
                sa = fmaf(f6, w1.z, sa);
                float sb = f1 * w0.y;
                sb = fmaf(f3, w0.w, sb);
                sb = fmaf(f5, w1.y, sb);
                sb = fmaf(f7, w1.w, sb);
                s[k] = sa + sb;
            }
            // 8 interleaved butterfly reductions: chains overlap, no stalls
            #pragma unroll
            for (int o = 32; o > 0; o >>= 1) {
                #pragma unroll
                for (int k = 0; k < 8; ++k)
                    s[k] += __shfl_xor(s[k], o, 64);
            }
            if (last && lane == 0) {
                #pragma unroll
                for (int k = 0; k < 8; ++k)
                    lnS_s[wave + 16 * (8 * b + k)] = __logf(s[k]);
            }
            #pragma unroll
            for (int k = 0; k < 8; ++k) s[k] = __builtin_amdgcn_rcpf(s[k]);
            // pass 2: t_j += K'_ij * r_i from registers (pure fma streaming)
            #pragma unroll
            for (int k = 0; k < 8; ++k) {
                const float r = s[k];
                float f0 = __uint_as_float(cur[k].x << 16);
                float f1 = __uint_as_float(cur[k].x & 0xffff0000u);
                float f2 = __uint_as_float(cur[k].y << 16);
                float f3 = __uint_as_float(cur[k].y & 0xffff0000u);
                float f4 = __uint_as_float(cur[k].z << 16);
                float f5 = __uint_as_float(cur[k].z & 0xffff0000u);
                float f6 = __uint_as_float(cur[k].w << 16);
                float f7 = __uint_as_float(cur[k].w & 0xffff0000u);
                t0 = fmaf(f0, r, t0); t1 = fmaf(f1, r, t1);
                t2 = fmaf(f2, r, t2); t3 = fmaf(f3, r, t3);
                t4 = fmaf(f4, r, t4); t5 = fmaf(f5, r, t5);
                t6 = fmaf(f6, r, t6); t7 = fmaf(f7, r, t7);
            }
            #pragma unroll
            for (int k = 0; k < 8; ++k) cur[k] = nxt[k];
            kp = np;
        }

        // cross-wave t reduction (measured: bank conflicts here are ~0.7% - ignore)
        *(float4*)(c_lds + wave * N + 8 * lane)     = make_float4(t0, t1, t2, t3);
        *(float4*)(c_lds + wave * N + 8 * lane + 4) = make_float4(t4, t5, t6, t7);
        __syncthreads();
        if (tid < N) {
            float cs = 0.f;
            #pragma unroll
            for (int w = 0; w < 16; ++w) cs += c_lds[w * N + tid];
            w_s[tid] = __builtin_amdgcn_rcpf(fmaxf(cs, 1e-38f));
        }
        __syncthreads();
    }

    // ---- epilogue: P = exp(A*SC - m_i - lnS_i + ln w_j) from fp32 A ----
    float* g_s  = c_lds;        // ln w  [N]
    float* rt_s = c_lds + N;    // -(m + lnS) [N]
    if (tid < N) {
        g_s[tid]  = __logf(w_s[tid]);
        rt_s[tid] = -(m_s[tid] + lnS_s[tid]);
    }
    __syncthreads();

    #pragma unroll 1
    for (int r = wave; r < N; r += 16) {
        const float rt = rt_s[r];
        const float4* rowp = (const float4*)(A + (size_t)r * N);
        float4 a0 = rowp[lane];
        float4 a1 = rowp[lane + 64];
        float4 g0 = *(const float4*)(g_s + 4 * lane);
        float4 g1 = *(const float4*)(g_s + 256 + 4 * lane);
        float4 o0, o1;
        o0.x = __expf(fmaf(a0.x, SC, rt) + g0.x);
        o0.y = __expf(fmaf(a0.y, SC, rt) + g0.y);
        o0.z = __expf(fmaf(a0.z, SC, rt) + g0.z);
        o0.w = __expf(fmaf(a0.w, SC, rt) + g0.w);
        o1.x = __expf(fmaf(a1.x, SC, rt) + g1.x);
        o1.y = __expf(fmaf(a1.y, SC, rt) + g1.y);
        o1.z = __expf(fmaf(a1.z, SC, rt) + g1.z);
        o1.w = __expf(fmaf(a1.w, SC, rt) + g1.w);
        float4* outp = (float4*)(out + (size_t)r * N);
        outp[lane]      = o0;
        outp[lane + 64] = o1;
    }
}

extern "C" void kernel_launch(void* const* d_in, const int* in_sizes, int n_in,
                              void* d_out, int out_size, void* d_ws, size_t ws_size,
                              hipStream_t stream) {
    const float* X = (const float*)d_in[0];
    float* P = (float*)d_out;
    const int batch = in_sizes[0] / (N * N);   // 128
    hipLaunchKernelGGL(sinkhorn_batch, dim3(batch), dim3(1024), 0, stream, X, P);
}